// Round 1
// baseline (173.714 us; speedup 1.0000x reference)
//
#include <hip/hip_runtime.h>
#include <hip/hip_bf16.h>
#include <math.h>
#include <stdint.h>

// Problem constants (fixed by reference)
#define T_ROWS 16384
#define D_DIM  4096
#define E_EXP  64
#define TOPK   8

// GEMM tiling
constexpr int BM = 64;          // rows per block
constexpr int BK = 64;          // k-chunk
constexpr int SPLITS = 4;       // split-D for occupancy
constexpr int DSPLIT = D_DIM / SPLITS;  // 1024

// ---------------------------------------------------------------------------
// K1: partial logits  part[s][row][e] = sum_{k in split s} h[row,k] * W[e,k]
// f32 VALU GEMM, 64x64 tile, 4x4 per thread, transposed padded LDS tiles.
// ---------------------------------------------------------------------------
__global__ __launch_bounds__(256, 4) void gemm_partial_kernel(
    const float* __restrict__ h, const float* __restrict__ W,
    float* __restrict__ part)
{
    const int tile  = blockIdx.x;     // row tile 0..T/BM-1
    const int split = blockIdx.y;     // 0..SPLITS-1
    const int row0  = tile * BM;
    const int kbase = split * DSPLIT;

    __shared__ float As[BK][BM + 4];     // [k][m], stride 68 (272B, 16B-aligned)
    __shared__ float Bs[BK][E_EXP + 4];  // [k][e]

    const int tid = threadIdx.x;
    const int tx = tid & 15;          // output col group
    const int ty = tid >> 4;          // output row group
    const int ldr = tid >> 4;         // staging row 0..15
    const int ldk = (tid & 15) * 4;   // staging k offset 0..60

    float acc[4][4] = {};

    for (int kb = 0; kb < DSPLIT; kb += BK) {
        const int k0 = kbase + kb;
        // stage h tile: 64 rows x 64 k (transposed into As[k][m])
        #pragma unroll
        for (int pass = 0; pass < 4; ++pass) {
            const int r = ldr + pass * 16;
            const float4 v = *(const float4*)&h[(size_t)(row0 + r) * D_DIM + k0 + ldk];
            As[ldk + 0][r] = v.x; As[ldk + 1][r] = v.y;
            As[ldk + 2][r] = v.z; As[ldk + 3][r] = v.w;
        }
        // stage W tile: 64 experts x 64 k (transposed into Bs[k][e])
        #pragma unroll
        for (int pass = 0; pass < 4; ++pass) {
            const int e = ldr + pass * 16;
            const float4 v = *(const float4*)&W[(size_t)e * D_DIM + k0 + ldk];
            Bs[ldk + 0][e] = v.x; Bs[ldk + 1][e] = v.y;
            Bs[ldk + 2][e] = v.z; Bs[ldk + 3][e] = v.w;
        }
        __syncthreads();

        #pragma unroll 16
        for (int k = 0; k < BK; ++k) {
            const float4 a = *(const float4*)&As[k][ty * 4];
            const float4 b = *(const float4*)&Bs[k][tx * 4];
            const float av[4] = {a.x, a.y, a.z, a.w};
            const float bv[4] = {b.x, b.y, b.z, b.w};
            #pragma unroll
            for (int i = 0; i < 4; ++i)
                #pragma unroll
                for (int j = 0; j < 4; ++j)
                    acc[i][j] = fmaf(av[i], bv[j], acc[i][j]);
        }
        __syncthreads();
    }

    // write partials (coalesced float4 per row)
    float* p = part + ((size_t)split * T_ROWS + row0) * E_EXP;
    #pragma unroll
    for (int i = 0; i < 4; ++i) {
        const int r = ty * 4 + i;
        float4 o;
        o.x = acc[i][0]; o.y = acc[i][1]; o.z = acc[i][2]; o.w = acc[i][3];
        *(float4*)&p[(size_t)r * E_EXP + tx * 4] = o;
    }
}

// ---------------------------------------------------------------------------
// K2: per-row epilogue. One wave per row, lane == expert.
// Outputs (flat, in return order): mask, probs, logits_clean, logits_sel.
// ---------------------------------------------------------------------------
__global__ __launch_bounds__(256) void epilogue_kernel(
    const float* __restrict__ part, const float* __restrict__ u,
    float* __restrict__ out, int splits)
{
    const int row  = blockIdx.x * 4 + (threadIdx.x >> 6);
    const int lane = threadIdx.x & 63;
    if (row >= T_ROWS) return;
    const size_t te = (size_t)T_ROWS * E_EXP;
    const size_t idx = (size_t)row * E_EXP + lane;

    // fixed-order reduction of split partials (deterministic)
    float logit = 0.f;
    for (int s = 0; s < splits; ++s)
        logit += part[((size_t)s * T_ROWS + row) * E_EXP + lane];

    out[2 * te + idx] = logit;             // logits_clean

    // softmax over experts (router_temp = 1)
    float m = logit;
    #pragma unroll
    for (int off = 32; off; off >>= 1) m = fmaxf(m, __shfl_xor(m, off));
    const float p = expf(logit - m);
    float ssum = p;
    #pragma unroll
    for (int off = 32; off; off >>= 1) ssum += __shfl_xor(ssum, off);
    out[1 * te + idx] = p / ssum;          // probs

    // Gumbel noise, select_temp = 1, tau = 1
    const float uv = u[idx];
    const float g = -logf(-logf(uv));
    const float sel = logit + g;
    out[3 * te + idx] = sel;               // logits_sel

    // top-8 mask: iteratively take max, ties -> lowest lane (matches lax.top_k)
    float v = sel;
    bool chosen = false;
    #pragma unroll
    for (int it = 0; it < TOPK; ++it) {
        float mv = v;
        #pragma unroll
        for (int off = 32; off; off >>= 1) mv = fmaxf(mv, __shfl_xor(mv, off));
        const unsigned long long b = __ballot(v == mv);
        const int sl = __ffsll((long long)b) - 1;
        if (lane == sl) { chosen = true; v = -INFINITY; }
    }
    out[idx] = chosen ? 1.0f : 0.0f;       // mask
}

// ---------------------------------------------------------------------------
extern "C" void kernel_launch(void* const* d_in, const int* in_sizes, int n_in,
                              void* d_out, int out_size, void* d_ws, size_t ws_size,
                              hipStream_t stream) {
    const float* h = (const float*)d_in[0];
    const float* W = (const float*)d_in[1];
    const float* u = (const float*)d_in[2];
    float* out = (float*)d_out;

    const size_t te = (size_t)T_ROWS * E_EXP;
    const size_t need = (size_t)SPLITS * te * sizeof(float);

    int splits;
    float* part;
    if (ws_size >= need) {
        splits = SPLITS;
        part = (float*)d_ws;
    } else {
        // fallback: single split, accumulate directly into logits_clean slot
        splits = 1;
        part = out + 2 * te;
    }

    dim3 grid1(T_ROWS / BM, splits);
    hipLaunchKernelGGL(gemm_partial_kernel, grid1, dim3(256), 0, stream, h, W, part);

    dim3 grid2(T_ROWS / 4);
    hipLaunchKernelGGL(epilogue_kernel, grid2, dim3(256), 0, stream, part, u, out, splits);
}

// Round 2
// 165.531 us; speedup vs baseline: 1.0494x; 1.0494x over previous
//
#include <hip/hip_runtime.h>
#include <hip/hip_bf16.h>
#include <math.h>
#include <stdint.h>

// Problem constants
#define T_ROWS 16384
#define D_DIM  4096
#define E_EXP  64
#define TOPK   8

constexpr int BM = 64;          // rows per block (full E=64 per block)
constexpr int BK = 64;          // k-tile
constexpr int NT = 512;         // 8 waves
constexpr float H_SCALE = 16.0f;    // exact pow2 scaling keeps f16 lo parts normal
constexpr float W_SCALE = 64.0f;
constexpr float INV_SCALE = 1.0f / (16.0f * 64.0f);

typedef _Float16 f16x8 __attribute__((ext_vector_type(8)));
typedef _Float16 f16x4 __attribute__((ext_vector_type(4)));
typedef float    f32x4 __attribute__((ext_vector_type(4)));

// LDS: four f16 tiles [row][k] (row stride 128B, XOR-swizzled 16B chunks),
// reused as f32 logits buffer for the fused epilogue.
union SMem {
    struct {
        _Float16 Ahi[BM * BK];
        _Float16 Alo[BM * BK];
        _Float16 Bhi[E_EXP * BK];
        _Float16 Blo[E_EXP * BK];
    } t;
    float logits[BM * (E_EXP + 1)];
};

// swizzled byte offset within a tile: row stride 128B, XOR 16B-chunk idx with (row&7)
__device__ __forceinline__ int swz(int row, int byteInRow) {
    return row * 128 + ((((byteInRow >> 4) ^ (row & 7)) << 4) | (byteInRow & 15));
}

__device__ __forceinline__ void cvt4(const float4 v, const float s, f16x4& hi, f16x4& lo) {
    const float x[4] = {v.x * s, v.y * s, v.z * s, v.w * s};
    #pragma unroll
    for (int j = 0; j < 4; ++j) {
        _Float16 h = (_Float16)x[j];
        hi[j] = h;
        lo[j] = (_Float16)(x[j] - (float)h);
    }
}

__global__ __launch_bounds__(NT) void router_fused_kernel(
    const float* __restrict__ h, const float* __restrict__ W,
    const float* __restrict__ u, float* __restrict__ out)
{
    __shared__ SMem sm;
    const int tid  = threadIdx.x;
    const int wv   = tid >> 6;        // wave 0..7
    const int lane = tid & 63;
    const int mt   = wv & 3;          // m-tile (16 rows)
    const int eh   = wv >> 2;         // e-half (2 e-tiles of 16)
    const int row0 = blockIdx.x * BM;

    // staging: thread covers (srow, srow+32) x 4 floats at sk4
    const int srow = tid >> 4;        // 0..31
    const int sk4  = (tid & 15) * 4;  // 0..60

    f32x4 acc[2] = {};                // 2 e-tiles x f32x4 accumulator

    float4 ra[2], rb[2];
    // prologue: load k-tile 0
    {
        const float* hp = h + (size_t)(row0 + srow) * D_DIM + sk4;
        ra[0] = *(const float4*)hp;
        ra[1] = *(const float4*)(hp + (size_t)32 * D_DIM);
        const float* wp = W + (size_t)srow * D_DIM + sk4;
        rb[0] = *(const float4*)wp;
        rb[1] = *(const float4*)(wp + (size_t)32 * D_DIM);
    }

    const int sbyte = (sk4 * 2) & 15;           // 0 or 8
    const int schunkbase = sk4 >> 3;            // 16B chunk index base

    for (int it = 0; it < D_DIM / BK; ++it) {
        // convert + write current regs into LDS (hi/lo f16, swizzled)
        #pragma unroll
        for (int p = 0; p < 2; ++p) {
            const int r = srow + p * 32;
            const int sb = r * 128 + ((((schunkbase) ^ (r & 7)) << 4) | sbyte);
            f16x4 hi, lo;
            cvt4(ra[p], H_SCALE, hi, lo);
            *(f16x4*)((char*)sm.t.Ahi + sb) = hi;
            *(f16x4*)((char*)sm.t.Alo + sb) = lo;
            cvt4(rb[p], W_SCALE, hi, lo);
            *(f16x4*)((char*)sm.t.Bhi + sb) = hi;
            *(f16x4*)((char*)sm.t.Blo + sb) = lo;
        }
        __syncthreads();

        // issue next k-tile global loads (land during MFMA phase)
        if (it + 1 < D_DIM / BK) {
            const int k0 = (it + 1) * BK;
            const float* hp = h + (size_t)(row0 + srow) * D_DIM + k0 + sk4;
            ra[0] = *(const float4*)hp;
            ra[1] = *(const float4*)(hp + (size_t)32 * D_DIM);
            const float* wp = W + (size_t)srow * D_DIM + k0 + sk4;
            rb[0] = *(const float4*)wp;
            rb[1] = *(const float4*)(wp + (size_t)32 * D_DIM);
        }

        // fragments + MFMA: wave = m-tile mt, e-tiles {eh*2, eh*2+1}
        #pragma unroll
        for (int kc = 0; kc < 2; ++kc) {
            const int arow = mt * 16 + (lane & 15);
            const int kb   = (kc * 32 + (lane >> 4) * 8) * 2;   // byte offset in row
            const int ab   = swz(arow, kb);
            const f16x8 ah = *(const f16x8*)((const char*)sm.t.Ahi + ab);
            const f16x8 al = *(const f16x8*)((const char*)sm.t.Alo + ab);
            #pragma unroll
            for (int et = 0; et < 2; ++et) {
                const int erow = (eh * 2 + et) * 16 + (lane & 15);
                const int bb   = swz(erow, kb);
                const f16x8 bh = *(const f16x8*)((const char*)sm.t.Bhi + bb);
                const f16x8 bl = *(const f16x8*)((const char*)sm.t.Blo + bb);
                acc[et] = __builtin_amdgcn_mfma_f32_16x16x32_f16(ah, bh, acc[et], 0, 0, 0);
                acc[et] = __builtin_amdgcn_mfma_f32_16x16x32_f16(ah, bl, acc[et], 0, 0, 0);
                acc[et] = __builtin_amdgcn_mfma_f32_16x16x32_f16(al, bh, acc[et], 0, 0, 0);
            }
        }
        __syncthreads();
    }

    // ---- fused epilogue: dump logits to LDS (tiles are dead now) ----
    #pragma unroll
    for (int et = 0; et < 2; ++et)
        #pragma unroll
        for (int r = 0; r < 4; ++r) {
            const int row = mt * 16 + (lane >> 4) * 4 + r;   // C/D: row = 4*(l>>4)+reg
            const int col = (eh * 2 + et) * 16 + (lane & 15);
            sm.logits[row * (E_EXP + 1) + col] = acc[et][r] * INV_SCALE;
        }
    __syncthreads();

    const size_t te = (size_t)T_ROWS * E_EXP;
    // 8 waves x 8 rows each; lane = expert
    for (int rr = 0; rr < 8; ++rr) {
        const int row = wv * 8 + rr;
        const int gr  = row0 + row;
        const size_t idx = (size_t)gr * E_EXP + lane;
        const float val = sm.logits[row * (E_EXP + 1) + lane];

        out[2 * te + idx] = val;                      // logits_clean

        float m = val;
        #pragma unroll
        for (int off = 32; off; off >>= 1) m = fmaxf(m, __shfl_xor(m, off));
        const float p = expf(val - m);
        float ssum = p;
        #pragma unroll
        for (int off = 32; off; off >>= 1) ssum += __shfl_xor(ssum, off);
        out[1 * te + idx] = p / ssum;                 // probs

        const float uv = u[idx];
        const float g = -logf(-logf(uv));
        const float sel = val + g;
        out[3 * te + idx] = sel;                      // logits_sel

        // top-8, ties -> lowest lane (matches lax.top_k ordering)
        float v = sel;
        bool chosen = false;
        #pragma unroll
        for (int itk = 0; itk < TOPK; ++itk) {
            float mv = v;
            #pragma unroll
            for (int off = 32; off; off >>= 1) mv = fmaxf(mv, __shfl_xor(mv, off));
            const unsigned long long b = __ballot(v == mv);
            const int sl = __ffsll((long long)b) - 1;
            if (lane == sl) { chosen = true; v = -INFINITY; }
        }
        out[idx] = chosen ? 1.0f : 0.0f;              // mask
    }
}

extern "C" void kernel_launch(void* const* d_in, const int* in_sizes, int n_in,
                              void* d_out, int out_size, void* d_ws, size_t ws_size,
                              hipStream_t stream) {
    const float* h = (const float*)d_in[0];
    const float* W = (const float*)d_in[1];
    const float* u = (const float*)d_in[2];
    float* out = (float*)d_out;

    hipLaunchKernelGGL(router_fused_kernel, dim3(T_ROWS / BM), dim3(NT), 0, stream,
                       h, W, u, out);
}